// Round 2
// baseline (286.195 us; speedup 1.0000x reference)
//
#include <hip/hip_runtime.h>
#include <math.h>

#define NB 4096
#define PAD 2048
#define BLOCK 256
#define ITERS (NB / 4 / BLOCK)   // 4 float4 iterations per thread

typedef float f32x4 __attribute__((ext_vector_type(4)));

__device__ __forceinline__ int mirror_idx(int i) {
    // valid for i in [-PAD, NB+PAD-2]; single reflection
    i = ::abs(i);
    return (i < NB) ? i : (2 * (NB - 1) - i);
}

// Precompute p = sigmoid(logits), lsp = log_sigmoid(logits), lsn = log_sigmoid(-logits)
// into ws[0..NB), ws[NB..2NB), ws[2NB..3NB).
__global__ void fbmp_precompute(const float* __restrict__ logits, float* __restrict__ ws) {
    int j = blockIdx.x * blockDim.x + threadIdx.x;
    if (j >= NB) return;
    float x = logits[j];
    double xd = (double)x;
    float e = (float)exp(-xd);
    float p = 1.0f / (1.0f + e);
    float lsp = (float)(-log1p(exp(-xd)));  // log_sigmoid(x)
    float lsn = (float)(-log1p(exp(xd)));   // log_sigmoid(-x)
    ws[j] = p;
    ws[NB + j] = lsp;
    ws[2 * NB + j] = lsn;
}

__global__ __launch_bounds__(BLOCK, 8) void fbmp_main(
    const float* __restrict__ u, const int* __restrict__ shift,
    const float* __restrict__ ws,
    float* __restrict__ masks, float* __restrict__ logp)
{
    __shared__ float sred[BLOCK / 64];  // per-wave partial sums (only LDS left)

    const int b = blockIdx.x;
    const int s = shift[b] - PAD;       // early scalar load

    const float* __restrict__ urow = u + (size_t)b * NB;
    const float4* __restrict__ u4   = (const float4*)urow;
    const float4* __restrict__ p4   = (const float4*)(ws);
    const float4* __restrict__ lsp4 = (const float4*)(ws + NB);
    const float4* __restrict__ lsn4 = (const float4*)(ws + 2 * NB);

    // ---- phase 1: log-prob partial, software-pipelined loads ----
    // (math, per-thread element order, association identical to verified kernel)
    float acc = 0.0f;
    {
        const int t = threadIdx.x;
        float4 uv = u4[t];
        float4 pv = p4[t];
        float4 ap = lsp4[t];
        float4 an = lsn4[t];
        #pragma unroll
        for (int it = 0; it < ITERS; ++it) {
            float4 nuv, npv, nap, nan2;
            if (it + 1 < ITERS) {           // compile-time resolved (full unroll)
                const int i1 = t + (it + 1) * BLOCK;
                nuv = u4[i1];
                npv = p4[i1];
                nap = lsp4[i1];
                nan2 = lsn4[i1];
            }
            bool c0 = uv.x < pv.x;
            bool c1 = uv.y < pv.y;
            bool c2 = uv.z < pv.z;
            bool c3 = uv.w < pv.w;
            acc += (c0 ? ap.x : an.x) + (c1 ? ap.y : an.y)
                 + (c2 ? ap.z : an.z) + (c3 ? ap.w : an.w);
            uv = nuv; pv = npv; ap = nap; an = nan2;
        }
    }

    // per-wave reduction, publish partials -- NO barrier yet (hidden behind phase 2)
    #pragma unroll
    for (int off = 32; off > 0; off >>= 1)
        acc += __shfl_down(acc, off, 64);
    const int lane = threadIdx.x & 63;
    const int wid  = threadIdx.x >> 6;
    if (lane == 0) sred[wid] = acc;

    // ---- phase 2: reflect-pad shifted window, recomputed directly from global ----
    // masks[b][k] = (u[b][j] < p[j]) with j = mirror(k+s): no LDS staging, no
    // barrier before stores. Gathered u[j]/p[j] are piecewise-contiguous scalar
    // loads hitting L1/L2/L3 (row just streamed; p hot chip-wide; u L3-resident).
    // Stores: wide nontemporal dwordx4, write-once data stays out of L3.
    float* __restrict__ mrow = masks + (size_t)b * NB;
    #pragma unroll
    for (int it = 0; it < ITERS; ++it) {
        const int i = threadIdx.x + it * BLOCK;
        const int k = 4 * i + s;
        const int j0 = mirror_idx(k + 0);
        const int j1 = mirror_idx(k + 1);
        const int j2 = mirror_idx(k + 2);
        const int j3 = mirror_idx(k + 3);
        f32x4 o;
        o.x = (urow[j0] < ws[j0]) ? 1.0f : 0.0f;
        o.y = (urow[j1] < ws[j1]) ? 1.0f : 0.0f;
        o.z = (urow[j2] < ws[j2]) ? 1.0f : 0.0f;
        o.w = (urow[j3] < ws[j3]) ? 1.0f : 0.0f;
        __builtin_nontemporal_store(o, (f32x4*)mrow + i);
    }

    // ---- finalize logp (tiny; barrier sits after all stores are issued) ----
    __syncthreads();
    if (threadIdx.x == 0) {
        float t = 0.0f;
        #pragma unroll
        for (int w = 0; w < BLOCK / 64; ++w) t += sred[w];
        logp[b] = t;
    }
}

extern "C" void kernel_launch(void* const* d_in, const int* in_sizes, int n_in,
                              void* d_out, int out_size, void* d_ws, size_t ws_size,
                              hipStream_t stream) {
    const float* logits = (const float*)d_in[0];
    const float* u      = (const float*)d_in[1];
    const int*   shift  = (const int*)d_in[2];
    const int B = in_sizes[2];

    float* ws    = (float*)d_ws;                    // 3*NB floats
    float* masks = (float*)d_out;                   // B*NB
    float* logp  = (float*)d_out + (size_t)B * NB;  // B

    fbmp_precompute<<<(NB + 255) / 256, 256, 0, stream>>>(logits, ws);
    fbmp_main<<<B, BLOCK, 0, stream>>>(u, shift, ws, masks, logp);
}

// Round 3
// 246.938 us; speedup vs baseline: 1.1590x; 1.1590x over previous
//
#include <hip/hip_runtime.h>
#include <math.h>

#define NB 4096
#define PAD 2048
#define BLOCK 256
#define ROWS 8                    // rows per block (persistent pipeline)
#define QITERS (NB / 4 / BLOCK)   // 4 float4 groups per thread

typedef float f32x4 __attribute__((ext_vector_type(4)));

__device__ __forceinline__ int mirror_idx(int i) {
    // valid for i in [-PAD, NB+PAD-2]; single reflection
    i = ::abs(i);
    return (i < NB) ? i : (2 * (NB - 1) - i);
}

// Precompute p = sigmoid(logits), lsp = log_sigmoid(logits), lsn = log_sigmoid(-logits)
__global__ void fbmp_precompute(const float* __restrict__ logits, float* __restrict__ ws) {
    int j = blockIdx.x * blockDim.x + threadIdx.x;
    if (j >= NB) return;
    float x = logits[j];
    double xd = (double)x;
    float e = (float)exp(-xd);
    float p = 1.0f / (1.0f + e);
    float lsp = (float)(-log1p(exp(-xd)));  // log_sigmoid(x)
    float lsn = (float)(-log1p(exp(xd)));   // log_sigmoid(-x)
    ws[j] = p;
    ws[NB + j] = lsp;
    ws[2 * NB + j] = lsn;
}

__global__ __launch_bounds__(BLOCK, 4) void fbmp_main(
    const float* __restrict__ u, const int* __restrict__ shift,
    const float* __restrict__ ws,
    float* __restrict__ masks, float* __restrict__ logp, int B)
{
    __shared__ float sg[2][NB];          // double-buffered grid row
    __shared__ float sred[2][BLOCK / 64];

    const int t  = threadIdx.x;
    const int b0 = blockIdx.x * ROWS;
    const int nrows = (B - b0 < ROWS) ? (B - b0) : ROWS;  // block-uniform

    const float4* __restrict__ p4   = (const float4*)(ws);
    const float4* __restrict__ lsp4 = (const float4*)(ws + NB);
    const float4* __restrict__ lsn4 = (const float4*)(ws + 2 * NB);

    // ---- tables: load ONCE per block into registers (block-invariant) ----
    float4 pv[QITERS], ap[QITERS], an[QITERS];
    #pragma unroll
    for (int it = 0; it < QITERS; ++it) {
        pv[it] = p4[t + it * BLOCK];
        ap[it] = lsp4[t + it * BLOCK];
        an[it] = lsn4[t + it * BLOCK];
    }

    // ---- prologue: row 0's u into registers ----
    float4 uv[QITERS];
    {
        const float4* __restrict__ u4 = (const float4*)(u + (size_t)b0 * NB);
        #pragma unroll
        for (int it = 0; it < QITERS; ++it) uv[it] = u4[t + it * BLOCK];
    }
    int s_cur = shift[b0] - PAD;

    const int lane = t & 63;
    const int wid  = t >> 6;

    for (int r = 0; r < nrows; ++r) {
        const int buf = r & 1;

        // ---- compute row r: compares + logp partial (order identical to verified kernel) ----
        float acc = 0.0f;
        #pragma unroll
        for (int it = 0; it < QITERS; ++it) {
            bool c0 = uv[it].x < pv[it].x;
            bool c1 = uv[it].y < pv[it].y;
            bool c2 = uv[it].z < pv[it].z;
            bool c3 = uv[it].w < pv[it].w;
            acc += (c0 ? ap[it].x : an[it].x) + (c1 ? ap[it].y : an[it].y)
                 + (c2 ? ap[it].z : an[it].z) + (c3 ? ap[it].w : an[it].w);
            float4 g;
            g.x = c0 ? 1.0f : 0.0f;
            g.y = c1 ? 1.0f : 0.0f;
            g.z = c2 ? 1.0f : 0.0f;
            g.w = c3 ? 1.0f : 0.0f;
            ((float4*)sg[buf])[t + it * BLOCK] = g;
        }

        // wave reduction (unchanged tree), publish per-wave partials
        #pragma unroll
        for (int off = 32; off > 0; off >>= 1)
            acc += __shfl_down(acc, off, 64);
        if (lane == 0) sred[buf][wid] = acc;

        // ---- prefetch row r+1's u into regs BEFORE the barrier: its HBM
        //      latency hides under row r's gather+store phase ----
        int s_next = 0;
        if (r + 1 < nrows) {
            const float4* __restrict__ un4 =
                (const float4*)(u + (size_t)(b0 + r + 1) * NB);
            #pragma unroll
            for (int it = 0; it < QITERS; ++it) uv[it] = un4[t + it * BLOCK];
            s_next = shift[b0 + r + 1] - PAD;
        }

        __syncthreads();  // publishes sg[buf] + sred[buf]; only barrier per row

        // ---- gather + wide NT store of row r (reads sg[buf]; row r+1 writes sg[buf^1]) ----
        float* __restrict__ mrow = masks + (size_t)(b0 + r) * NB;
        const float* __restrict__ sgb = sg[buf];
        #pragma unroll
        for (int it = 0; it < QITERS; ++it) {
            const int i = t + it * BLOCK;
            const int k = 4 * i + s_cur;
            f32x4 o;
            o.x = sgb[mirror_idx(k + 0)];
            o.y = sgb[mirror_idx(k + 1)];
            o.z = sgb[mirror_idx(k + 2)];
            o.w = sgb[mirror_idx(k + 3)];
            __builtin_nontemporal_store(o, (f32x4*)mrow + i);
        }
        if (t == 0) {
            float tt = 0.0f;
            #pragma unroll
            for (int w = 0; w < BLOCK / 64; ++w) tt += sred[buf][w];
            logp[b0 + r] = tt;
        }
        s_cur = s_next;
    }
}

extern "C" void kernel_launch(void* const* d_in, const int* in_sizes, int n_in,
                              void* d_out, int out_size, void* d_ws, size_t ws_size,
                              hipStream_t stream) {
    const float* logits = (const float*)d_in[0];
    const float* u      = (const float*)d_in[1];
    const int*   shift  = (const int*)d_in[2];
    const int B = in_sizes[2];

    float* ws    = (float*)d_ws;                    // 3*NB floats
    float* masks = (float*)d_out;                   // B*NB
    float* logp  = (float*)d_out + (size_t)B * NB;  // B

    fbmp_precompute<<<(NB + 255) / 256, 256, 0, stream>>>(logits, ws);
    const int grid = (B + ROWS - 1) / ROWS;
    fbmp_main<<<grid, BLOCK, 0, stream>>>(u, shift, ws, masks, logp, B);
}

// Round 4
// 242.808 us; speedup vs baseline: 1.1787x; 1.0170x over previous
//
#include <hip/hip_runtime.h>
#include <math.h>

#define NB 4096
#define PAD 2048
#define BLOCK 256
#define QITERS (NB / 4 / BLOCK)   // 4 float4 groups per thread

typedef float f32x4 __attribute__((ext_vector_type(4)));

__device__ __forceinline__ int mirror_idx(int i) {
    // valid for i in [-PAD, NB+PAD-2]; single reflection
    i = ::abs(i);
    return (i < NB) ? i : (2 * (NB - 1) - i);
}

// Precompute p = sigmoid(logits), lsp = log_sigmoid(logits), lsn = log_sigmoid(-logits)
__global__ void fbmp_precompute(const float* __restrict__ logits, float* __restrict__ ws) {
    int j = blockIdx.x * blockDim.x + threadIdx.x;
    if (j >= NB) return;
    float x = logits[j];
    double xd = (double)x;
    float e = (float)exp(-xd);
    float p = 1.0f / (1.0f + e);
    float lsp = (float)(-log1p(exp(-xd)));  // log_sigmoid(x)
    float lsn = (float)(-log1p(exp(xd)));   // log_sigmoid(-x)
    ws[j] = p;
    ws[NB + j] = lsp;
    ws[2 * NB + j] = lsn;
}

// ---------------- Kernel A: pure read stream ----------------
// Reads u row, computes logp (bit-identical to the verified fused kernel) and
// packs the grid bits via wave ballots: u64 pb[row][it*4+wid][q] ... layout:
//   u64 index = (it*4 + wid)*4 + q ; bit l = (u[e] < p[e]) for
//   e = it*1024 + wid*256 + 4*l + q.
__global__ __launch_bounds__(BLOCK, 8) void fbmp_grid(
    const float* __restrict__ u, const float* __restrict__ ws,
    unsigned long long* __restrict__ pb, float* __restrict__ logp)
{
    __shared__ float sred[BLOCK / 64];

    const int b = blockIdx.x;
    const int t = threadIdx.x;
    const int lane = t & 63;
    const int wid  = t >> 6;

    const float4* __restrict__ u4   = (const float4*)(u + (size_t)b * NB);
    const float4* __restrict__ p4   = (const float4*)(ws);
    const float4* __restrict__ lsp4 = (const float4*)(ws + NB);
    const float4* __restrict__ lsn4 = (const float4*)(ws + 2 * NB);
    unsigned long long* __restrict__ pbrow = pb + (size_t)b * 64;

    float acc = 0.0f;
    #pragma unroll
    for (int it = 0; it < QITERS; ++it) {
        const int i = t + it * BLOCK;       // identical mapping to verified kernel
        float4 uv = u4[i];
        float4 pv = p4[i];
        float4 ap = lsp4[i];
        float4 an = lsn4[i];
        bool c0 = uv.x < pv.x;
        bool c1 = uv.y < pv.y;
        bool c2 = uv.z < pv.z;
        bool c3 = uv.w < pv.w;
        acc += (c0 ? ap.x : an.x) + (c1 ? ap.y : an.y)
             + (c2 ? ap.z : an.z) + (c3 ? ap.w : an.w);
        unsigned long long b0 = __ballot(c0);
        unsigned long long b1 = __ballot(c1);
        unsigned long long b2 = __ballot(c2);
        unsigned long long b3 = __ballot(c3);
        if (lane == 0) {
            unsigned long long* __restrict__ w8 = pbrow + ((it * 4 + wid) << 2);
            w8[0] = b0; w8[1] = b1; w8[2] = b2; w8[3] = b3;  // 32 B contiguous
        }
    }

    // block reduction of acc -> logp[b]  (unchanged tree)
    #pragma unroll
    for (int off = 32; off > 0; off >>= 1)
        acc += __shfl_down(acc, off, 64);
    if (lane == 0) sred[wid] = acc;
    __syncthreads();
    if (t == 0) {
        float tt = 0.0f;
        #pragma unroll
        for (int w = 0; w < BLOCK / 64; ++w) tt += sred[w];
        logp[b] = tt;
    }
}

// ---------------- Kernel B: pure write stream ----------------
// masks[b][k] = bit at j = mirror(k+s) of row b's packed grid.
// j -> u32 word: widx = ((j>>10)<<5) | (((j>>8)&3)<<3) | ((j&3)<<1) | ((j>>7)&1)
//      bitpos = (j>>2)&31
__global__ __launch_bounds__(BLOCK, 8) void fbmp_scatter(
    const unsigned long long* __restrict__ pb, const int* __restrict__ shift,
    float* __restrict__ masks)
{
    __shared__ unsigned int sw[128];   // 512 B of packed bits

    const int b = blockIdx.x;
    const int t = threadIdx.x;
    const int s = shift[b] - PAD;

    const unsigned int* __restrict__ pbrow32 = (const unsigned int*)(pb + (size_t)b * 64);
    if (t < 128) sw[t] = pbrow32[t];
    __syncthreads();

    float* __restrict__ mrow = masks + (size_t)b * NB;
    #pragma unroll
    for (int it = 0; it < QITERS; ++it) {
        const int i = t + it * BLOCK;
        const int k = 4 * i + s;
        f32x4 o;
        {
            const int j = mirror_idx(k + 0);
            const int widx = ((j >> 10) << 5) | (((j >> 8) & 3) << 3) | ((j & 3) << 1) | ((j >> 7) & 1);
            o.x = ((sw[widx] >> ((j >> 2) & 31)) & 1u) ? 1.0f : 0.0f;
        }
        {
            const int j = mirror_idx(k + 1);
            const int widx = ((j >> 10) << 5) | (((j >> 8) & 3) << 3) | ((j & 3) << 1) | ((j >> 7) & 1);
            o.y = ((sw[widx] >> ((j >> 2) & 31)) & 1u) ? 1.0f : 0.0f;
        }
        {
            const int j = mirror_idx(k + 2);
            const int widx = ((j >> 10) << 5) | (((j >> 8) & 3) << 3) | ((j & 3) << 1) | ((j >> 7) & 1);
            o.z = ((sw[widx] >> ((j >> 2) & 31)) & 1u) ? 1.0f : 0.0f;
        }
        {
            const int j = mirror_idx(k + 3);
            const int widx = ((j >> 10) << 5) | (((j >> 8) & 3) << 3) | ((j & 3) << 1) | ((j >> 7) & 1);
            o.w = ((sw[widx] >> ((j >> 2) & 31)) & 1u) ? 1.0f : 0.0f;
        }
        __builtin_nontemporal_store(o, (f32x4*)mrow + i);
    }
}

// ---------------- Fallback: round-0 fused kernel (proven 80 us) ----------------
__global__ __launch_bounds__(BLOCK) void fbmp_fused(
    const float* __restrict__ u, const int* __restrict__ shift,
    const float* __restrict__ ws,
    float* __restrict__ masks, float* __restrict__ logp)
{
    __shared__ float sg[NB];
    __shared__ float sred[BLOCK / 64];

    const int b = blockIdx.x;
    const float4* __restrict__ u4   = (const float4*)(u + (size_t)b * NB);
    const float4* __restrict__ p4   = (const float4*)(ws);
    const float4* __restrict__ lsp4 = (const float4*)(ws + NB);
    const float4* __restrict__ lsn4 = (const float4*)(ws + 2 * NB);

    float acc = 0.0f;
    for (int i = threadIdx.x; i < NB / 4; i += BLOCK) {
        float4 uv = u4[i];
        float4 pv = p4[i];
        float4 ap = lsp4[i];
        float4 an = lsn4[i];
        bool c0 = uv.x < pv.x;
        bool c1 = uv.y < pv.y;
        bool c2 = uv.z < pv.z;
        bool c3 = uv.w < pv.w;
        acc += (c0 ? ap.x : an.x) + (c1 ? ap.y : an.y)
             + (c2 ? ap.z : an.z) + (c3 ? ap.w : an.w);
        float4 g;
        g.x = c0 ? 1.0f : 0.0f;
        g.y = c1 ? 1.0f : 0.0f;
        g.z = c2 ? 1.0f : 0.0f;
        g.w = c3 ? 1.0f : 0.0f;
        ((float4*)sg)[i] = g;
    }
    #pragma unroll
    for (int off = 32; off > 0; off >>= 1)
        acc += __shfl_down(acc, off, 64);
    const int lane = threadIdx.x & 63;
    const int wid  = threadIdx.x >> 6;
    if (lane == 0) sred[wid] = acc;
    __syncthreads();
    if (threadIdx.x == 0) {
        float t = 0.0f;
        #pragma unroll
        for (int w = 0; w < BLOCK / 64; ++w) t += sred[w];
        logp[b] = t;
    }
    const int s = shift[b] - PAD;
    float4* __restrict__ m4 = (float4*)(masks + (size_t)b * NB);
    for (int i = threadIdx.x; i < NB / 4; i += BLOCK) {
        int k = 4 * i + s;
        float4 o;
        o.x = sg[mirror_idx(k + 0)];
        o.y = sg[mirror_idx(k + 1)];
        o.z = sg[mirror_idx(k + 2)];
        o.w = sg[mirror_idx(k + 3)];
        m4[i] = o;
    }
}

extern "C" void kernel_launch(void* const* d_in, const int* in_sizes, int n_in,
                              void* d_out, int out_size, void* d_ws, size_t ws_size,
                              hipStream_t stream) {
    const float* logits = (const float*)d_in[0];
    const float* u      = (const float*)d_in[1];
    const int*   shift  = (const int*)d_in[2];
    const int B = in_sizes[2];

    float* ws    = (float*)d_ws;                    // 3*NB floats (tables)
    float* masks = (float*)d_out;                   // B*NB
    float* logp  = (float*)d_out + (size_t)B * NB;  // B

    fbmp_precompute<<<(NB + 255) / 256, 256, 0, stream>>>(logits, ws);

    const size_t tbl_bytes = (size_t)3 * NB * sizeof(float);        // 48 KB
    const size_t pb_bytes  = (size_t)B * 64 * sizeof(unsigned long long);  // 4 MB @ B=8192
    if (ws_size >= tbl_bytes + pb_bytes) {
        unsigned long long* pb = (unsigned long long*)((char*)d_ws + tbl_bytes);
        fbmp_grid<<<B, BLOCK, 0, stream>>>(u, ws, pb, logp);
        fbmp_scatter<<<B, BLOCK, 0, stream>>>(pb, shift, masks);
    } else {
        fbmp_fused<<<B, BLOCK, 0, stream>>>(u, shift, ws, masks, logp);
    }
}